// Round 2
// baseline (225.167 us; speedup 1.0000x reference)
//
#include <hip/hip_runtime.h>
#include <hip/hip_bf16.h>
#include <math.h>

// Problem constants (fixed by reference: b=2, h=w=64, dim=256, attn_dim=128, HEAD=4)
#define N_TOK 4096
#define C_DIM 256
#define A_DIM 128
#define HEADS 4
#define HD    32
#define NBAT  2
#define BH    (NBAT * HEADS)

// (1/sqrt(32)) * log2(e) — folded into Q at projection time
#define SCALE_LOG2E 0.25503521f

#define SPLITS 2
#define KEYS_PER_SPLIT (N_TOK / SPLITS)

// padded LDS strides (shorts). 36 shorts = 72 B = 18 banks (odd*2): row reads
// at stride 18 banks visit 16 distinct bank groups for l15=0..15 -> <=2-way.
// 72 shorts = 144 B = 36 banks = 4 mod 32 -> stride-4 bank walk -> <=2-way.
#define KS 36
#define VS 72
#define PS 36

typedef __attribute__((ext_vector_type(8))) short short8;   // 8 bf16 frag
typedef __attribute__((ext_vector_type(4))) float floatx4;  // MFMA C/D frag

__device__ __forceinline__ unsigned short f2bf(float f) {
    unsigned int u = __float_as_uint(f);
    u = (u + 0x7fffu + ((u >> 16) & 1u)) >> 16;
    return (unsigned short)u;
}
__device__ __forceinline__ float bf2f(unsigned short u) {
    return __uint_as_float((unsigned int)u << 16);
}

// ---------------------------------------------------------------------------
// K1: fused QKV projection. 16 rows/block, 128 threads (thread t = out col t).
// Q is pre-scaled by SCALE_LOG2E so attention uses exp2(s) directly.
// Q,K out: bf16 [bh][n][32]; V out: bf16 [bh][32][n] (transposed).
// ---------------------------------------------------------------------------
#define QKV_ROWS 16
__global__ __launch_bounds__(128) void qkv_kernel(
    const float* __restrict__ query, const float* __restrict__ context,
    const float* __restrict__ Wq, const float* __restrict__ Wk,
    const float* __restrict__ Wv,
    unsigned short* __restrict__ Qb, unsigned short* __restrict__ Kb,
    unsigned short* __restrict__ Vb)
{
    __shared__ __align__(16) float qr[QKV_ROWS][C_DIM];
    __shared__ __align__(16) float cr[QKV_ROWS][C_DIM];
    const int tid = threadIdx.x;
    const long row0 = (long)blockIdx.x * QKV_ROWS;

    for (int i = tid; i < QKV_ROWS * (C_DIM / 4); i += 128) {
        const int r = i >> 6, c4 = i & 63;
        ((floatx4*)qr[r])[c4] = ((const floatx4*)(query + (row0 + r) * C_DIM))[c4];
        ((floatx4*)cr[r])[c4] = ((const floatx4*)(context + (row0 + r) * C_DIM))[c4];
    }
    __syncthreads();

    float aq[QKV_ROWS] = {}, ak[QKV_ROWS] = {}, av[QKV_ROWS] = {};
    for (int kk = 0; kk < C_DIM; kk += 4) {
        float wq4[4], wk4[4], wv4[4];
        #pragma unroll
        for (int u = 0; u < 4; u++) {
            wq4[u] = Wq[(kk + u) * A_DIM + tid];   // coalesced across threads
            wk4[u] = Wk[(kk + u) * A_DIM + tid];
            wv4[u] = Wv[(kk + u) * A_DIM + tid];
        }
        #pragma unroll
        for (int r = 0; r < QKV_ROWS; r++) {
            floatx4 q4 = *(floatx4*)&qr[r][kk];   // broadcast LDS reads (free)
            floatx4 c4 = *(floatx4*)&cr[r][kk];
            #pragma unroll
            for (int u = 0; u < 4; u++) {
                aq[r] = fmaf(q4[u], wq4[u], aq[r]);
                ak[r] = fmaf(c4[u], wk4[u], ak[r]);
                av[r] = fmaf(c4[u], wv4[u], av[r]);
            }
        }
    }

    const int h = tid >> 5, d = tid & 31;
    const long b = row0 >> 12;               // 4096 rows per batch
    const long nrow = row0 & (N_TOK - 1);
    const long bh = b * HEADS + h;

    unsigned short* qdst = Qb + (bh * N_TOK + nrow) * HD + d;
    unsigned short* kdst = Kb + (bh * N_TOK + nrow) * HD + d;
    #pragma unroll
    for (int r = 0; r < QKV_ROWS; r++) {
        qdst[r * HD] = f2bf(aq[r] * SCALE_LOG2E);   // fold softmax scale into Q
        kdst[r * HD] = f2bf(ak[r]);
    }
    short8 vv0, vv1;
    #pragma unroll
    for (int r = 0; r < 8; r++) { vv0[r] = (short)f2bf(av[r]); vv1[r] = (short)f2bf(av[r + 8]); }
    *(short8*)(Vb + (bh * HD + d) * N_TOK + nrow) = vv0;
    *(short8*)(Vb + (bh * HD + d) * N_TOK + nrow + 8) = vv1;
}

// ---------------------------------------------------------------------------
// K2: flash attention, no-max softmax, split-K=2.
// 1 wave = 32 queries (2 x 16 tiles sharing K/V frags); block = 4 waves = 128 q.
// Grid (32 qblocks, 8 bh, 2 splits). Per 64-key tile: stage K [key][dim,pad36]
// + V^T [dim][key,pad72]; per 32-key sub: 2 QK MFMA per q-tile -> exp2 ->
// P via padded wave-private LDS -> 2 PV MFMA per q-tile.
// Emits per-split normalized O (bf16) + softmax denominator l (fp32).
// ---------------------------------------------------------------------------
__global__ __launch_bounds__(256, 2) void attn_kernel(
    const unsigned short* __restrict__ Qb, const unsigned short* __restrict__ Kb,
    const unsigned short* __restrict__ Vb,
    unsigned short* __restrict__ AO, float* __restrict__ Lbuf)
{
    __shared__ __align__(16) unsigned short K_lds[64 * KS];        // 4.5 KB
    __shared__ __align__(16) unsigned short V_lds[HD * VS];        // 4.5 KB
    __shared__ __align__(16) unsigned short P_lds[4][2 * 16 * PS]; // 9 KB

    const int tid  = threadIdx.x;
    const int w    = tid >> 6;
    const int lane = tid & 63;
    const int quad = lane >> 4;
    const int l15  = lane & 15;
    const int bh   = blockIdx.y;
    const int z    = blockIdx.z;
    const int i0   = blockIdx.x * 128 + w * 32;

    const unsigned short* Qh = Qb + (long)bh * N_TOK * HD;
    const unsigned short* Kh = Kb + (long)bh * N_TOK * HD;
    const unsigned short* Vh = Vb + (long)bh * HD * N_TOK;

    const short8 qfA = *(const short8*)(Qh + (long)(i0 + l15) * HD + quad * 8);
    const short8 qfB = *(const short8*)(Qh + (long)(i0 + 16 + l15) * HD + quad * 8);

    floatx4 accA0 = {0.f,0.f,0.f,0.f}, accA1 = {0.f,0.f,0.f,0.f};
    floatx4 accB0 = {0.f,0.f,0.f,0.f}, accB1 = {0.f,0.f,0.f,0.f};
    floatx4 lA = {0.f,0.f,0.f,0.f}, lB = {0.f,0.f,0.f,0.f};

    // hoisted staging offsets
    const int  kst = (tid >> 2) * KS + (tid & 3) * 8;           // LDS K write
    const int  vst = (tid >> 3) * VS + (tid & 7) * 8;           // LDS V write
    const long vgl = (long)(tid >> 3) * N_TOK + (tid & 7) * 8;  // global V read
    unsigned short* Pw  = P_lds[w];
    unsigned short* PwB = P_lds[w] + 16 * PS;

    const int j_lo = z * KEYS_PER_SPLIT, j_hi = j_lo + KEYS_PER_SPLIT;
    for (int j0 = j_lo; j0 < j_hi; j0 += 64) {
        __syncthreads();
        *(short8*)&K_lds[kst] = *(const short8*)(Kh + (long)j0 * HD + tid * 8);
        *(short8*)&V_lds[vst] = *(const short8*)(Vh + vgl + j0);
        __syncthreads();

        #pragma unroll
        for (int sub = 0; sub < 2; sub++) {
            const int jb = sub * 32;
            short8 kf0 = *(short8*)&K_lds[(jb + l15) * KS + quad * 8];
            short8 kf1 = *(short8*)&K_lds[(jb + 16 + l15) * KS + quad * 8];
            const floatx4 zf = {0.f,0.f,0.f,0.f};
            floatx4 sA0 = __builtin_amdgcn_mfma_f32_16x16x32_bf16(qfA, kf0, zf, 0, 0, 0);
            floatx4 sA1 = __builtin_amdgcn_mfma_f32_16x16x32_bf16(qfA, kf1, zf, 0, 0, 0);
            floatx4 sB0 = __builtin_amdgcn_mfma_f32_16x16x32_bf16(qfB, kf0, zf, 0, 0, 0);
            floatx4 sB1 = __builtin_amdgcn_mfma_f32_16x16x32_bf16(qfB, kf1, zf, 0, 0, 0);

            floatx4 pA0, pA1, pB0, pB1;
            #pragma unroll
            for (int r = 0; r < 4; r++) {
                pA0[r] = __builtin_amdgcn_exp2f(sA0[r]);
                pA1[r] = __builtin_amdgcn_exp2f(sA1[r]);
                pB0[r] = __builtin_amdgcn_exp2f(sB0[r]);
                pB1[r] = __builtin_amdgcn_exp2f(sB1[r]);
                lA[r] += pA0[r] + pA1[r];
                lB[r] += pB0[r] + pB1[r];
            }

            #pragma unroll
            for (int r = 0; r < 4; r++) {
                const int rw = (quad * 4 + r) * PS;
                Pw[rw + l15]       = f2bf(pA0[r]);
                Pw[rw + 16 + l15]  = f2bf(pA1[r]);
                PwB[rw + l15]      = f2bf(pB0[r]);
                PwB[rw + 16 + l15] = f2bf(pB1[r]);
            }
            short8 pfA = *(short8*)&Pw[l15 * PS + quad * 8];
            short8 pfB = *(short8*)&PwB[l15 * PS + quad * 8];

            short8 vf0 = *(short8*)&V_lds[l15 * VS + jb + quad * 8];
            short8 vf1 = *(short8*)&V_lds[(16 + l15) * VS + jb + quad * 8];
            accA0 = __builtin_amdgcn_mfma_f32_16x16x32_bf16(pfA, vf0, accA0, 0, 0, 0);
            accA1 = __builtin_amdgcn_mfma_f32_16x16x32_bf16(pfA, vf1, accA1, 0, 0, 0);
            accB0 = __builtin_amdgcn_mfma_f32_16x16x32_bf16(pfB, vf0, accB0, 0, 0, 0);
            accB1 = __builtin_amdgcn_mfma_f32_16x16x32_bf16(pfB, vf1, accB1, 0, 0, 0);
        }
    }

    // reduce denominators across the 16 lanes of each quad (cols of C tile)
    #pragma unroll
    for (int off = 1; off < 16; off <<= 1) {
        #pragma unroll
        for (int r = 0; r < 4; r++) {
            lA[r] += __shfl_xor(lA[r], off);
            lB[r] += __shfl_xor(lB[r], off);
        }
    }

    const int b = bh >> 2, h = bh & 3;
    unsigned short* AOz = AO + (long)z * (NBAT * N_TOK * A_DIM);
    float* Lz = Lbuf + (long)z * (BH * N_TOK);
    #pragma unroll
    for (int r = 0; r < 4; r++) {
        const float invA = 1.0f / lA[r];
        const float invB = 1.0f / lB[r];
        const long rowA = (long)b * N_TOK + i0 + quad * 4 + r;
        const long rowB = rowA + 16;
        AOz[rowA * A_DIM + h * HD + l15]      = f2bf(accA0[r] * invA);
        AOz[rowA * A_DIM + h * HD + 16 + l15] = f2bf(accA1[r] * invA);
        AOz[rowB * A_DIM + h * HD + l15]      = f2bf(accB0[r] * invB);
        AOz[rowB * A_DIM + h * HD + 16 + l15] = f2bf(accB1[r] * invB);
        if (l15 == 0) {
            Lz[(long)bh * N_TOK + i0 + quad * 4 + r]      = lA[r];
            Lz[(long)bh * N_TOK + i0 + 16 + quad * 4 + r] = lB[r];
        }
    }
}

// ---------------------------------------------------------------------------
// K3: combine split-K partials + out-projection.
// out = ((O0*l0 + O1*l1)/(l0+l1)) @ Wo.  16 rows/block, 256 threads.
// ---------------------------------------------------------------------------
#define OP_ROWS 16
__global__ __launch_bounds__(256) void outproj_kernel(
    const unsigned short* __restrict__ AO, const float* __restrict__ Lbuf,
    const float* __restrict__ Wo, float* __restrict__ out)
{
    __shared__ __align__(16) float a_lds[OP_ROWS][A_DIM];
    const int tid = threadIdx.x;
    const long row0 = (long)blockIdx.x * OP_ROWS;

    {   // combine the two split partials while staging (8 elems per thread)
        const int r = tid >> 4;
        const int c0 = (tid & 15) * 8;
        const long row = row0 + r;
        const int b = (int)(row >> 12);
        const int n = (int)(row & (N_TOK - 1));
        const int h = c0 >> 5;
        const long bhn = (long)(b * HEADS + h) * N_TOK + n;
        const float l0 = Lbuf[bhn];
        const float l1 = Lbuf[(long)BH * N_TOK + bhn];
        const float inv = 1.0f / (l0 + l1);
        const float w0 = l0 * inv, w1 = l1 * inv;
        short8 a0 = *(const short8*)(AO + row * A_DIM + c0);
        short8 a1 = *(const short8*)(AO + (long)NBAT * N_TOK * A_DIM + row * A_DIM + c0);
        #pragma unroll
        for (int j = 0; j < 8; j++)
            a_lds[r][c0 + j] = w0 * bf2f((unsigned short)a0[j]) +
                               w1 * bf2f((unsigned short)a1[j]);
    }
    __syncthreads();

    float acc[OP_ROWS] = {};
    for (int kk = 0; kk < A_DIM; kk += 4) {
        float w4[4];
        #pragma unroll
        for (int u = 0; u < 4; u++) w4[u] = Wo[(kk + u) * C_DIM + tid];
        #pragma unroll
        for (int r = 0; r < OP_ROWS; r++) {
            floatx4 a4 = *(floatx4*)&a_lds[r][kk];
            #pragma unroll
            for (int u = 0; u < 4; u++) acc[r] = fmaf(a4[u], w4[u], acc[r]);
        }
    }
    #pragma unroll
    for (int r = 0; r < OP_ROWS; r++) out[(row0 + r) * C_DIM + tid] = acc[r];
}

// ---------------------------------------------------------------------------
extern "C" void kernel_launch(void* const* d_in, const int* in_sizes, int n_in,
                              void* d_out, int out_size, void* d_ws, size_t ws_size,
                              hipStream_t stream)
{
    const float* query   = (const float*)d_in[0];
    const float* context = (const float*)d_in[1];
    const float* Wq      = (const float*)d_in[2];
    const float* Wk      = (const float*)d_in[3];
    const float* Wv      = (const float*)d_in[4];
    const float* Wo      = (const float*)d_in[5];
    float* out = (float*)d_out;

    char* ws = (char*)d_ws;
    unsigned short* Qb = (unsigned short*)(ws);               // 2 MB [bh][n][32]
    unsigned short* Kb = (unsigned short*)(ws + (2 << 20));   // 2 MB [bh][n][32]
    unsigned short* Vb = (unsigned short*)(ws + (4 << 20));   // 2 MB [bh][32][n]
    unsigned short* AO = (unsigned short*)(ws + (6 << 20));   // 4 MB [2][b*n][128] bf16
    float*          Lb = (float*)(ws + (10 << 20));           // 256 KB [2][bh][n]

    qkv_kernel<<<dim3(8192 / QKV_ROWS), dim3(128), 0, stream>>>(
        query, context, Wq, Wk, Wv, Qb, Kb, Vb);
    attn_kernel<<<dim3(N_TOK / 128, BH, SPLITS), dim3(256), 0, stream>>>(
        Qb, Kb, Vb, AO, Lb);
    outproj_kernel<<<dim3(8192 / OP_ROWS), dim3(256), 0, stream>>>(AO, Lb, Wo, out);
}

// Round 4
// 170.783 us; speedup vs baseline: 1.3184x; 1.3184x over previous
//
#include <hip/hip_runtime.h>
#include <hip/hip_bf16.h>
#include <math.h>

// Problem constants (fixed by reference: b=2, h=w=64, dim=256, attn_dim=128, HEAD=4)
#define N_TOK 4096
#define C_DIM 256
#define A_DIM 128
#define HEADS 4
#define HD    32
#define NBAT  2
#define BH    (NBAT * HEADS)

// (1/sqrt(32)) * log2(e) — folded into Wq at pack time
#define SCALE_LOG2E 0.25503521f

#define SPLITS 2
#define KEYS_PER_SPLIT (N_TOK / SPLITS)

// padded LDS strides for attention (shorts)
#define KS 36
#define VS 72
#define PS 36

typedef __attribute__((ext_vector_type(8))) short short8;   // 8 bf16 frag
typedef __attribute__((ext_vector_type(4))) short short4_t; // 4 bf16
typedef __attribute__((ext_vector_type(4))) float floatx4;  // MFMA C/D frag

__device__ __forceinline__ unsigned short f2bf(float f) {
    unsigned int u = __float_as_uint(f);
    u = (u + 0x7fffu + ((u >> 16) & 1u)) >> 16;
    return (unsigned short)u;
}
__device__ __forceinline__ float bf2f(unsigned short u) {
    return __uint_as_float((unsigned int)u << 16);
}

// ---------------------------------------------------------------------------
// K0: pack weights fp32 -> bf16 in B-fragment order.
// Layout: Wp[wid][step s][tile t][lane][j]  (wid: 0=Wq(scaled) 1=Wk 2=Wv 3=Wo)
// B-frag semantics: lane=(quad,l15) holds B[k = quad*8+j][n = t*16+l15].
// qkv weights: K=256 (8 steps), N=128 (8 tiles). Wo: K=128 (4 steps), N=256 (16).
// ---------------------------------------------------------------------------
__global__ __launch_bounds__(256) void wpack_kernel(
    const float* __restrict__ Wq, const float* __restrict__ Wk,
    const float* __restrict__ Wv, const float* __restrict__ Wo,
    unsigned short* __restrict__ Wp)
{
    const int chunk = blockIdx.x * 256 + threadIdx.x;  // [0, 16384): 8 shorts each
    const int wid = chunk >> 12;
    const int c = chunk & 4095;
    const int lane = c & 63, quad = lane >> 4, l15 = lane & 15;
    short8 v;
    if (wid < 3) {
        const int s = c >> 9, t = (c >> 6) & 7;
        const float* W = (wid == 0) ? Wq : ((wid == 1) ? Wk : Wv);
        const float scale = (wid == 0) ? SCALE_LOG2E : 1.0f;
        const int src = (s * 32 + quad * 8) * A_DIM + t * 16 + l15;
        #pragma unroll
        for (int j = 0; j < 8; j++) v[j] = (short)f2bf(W[src + j * A_DIM] * scale);
    } else {
        const int s = c >> 10, t = (c >> 6) & 15;
        const int src = (s * 32 + quad * 8) * C_DIM + t * 16 + l15;
        #pragma unroll
        for (int j = 0; j < 8; j++) v[j] = (short)f2bf(Wo[src + j * C_DIM]);
    }
    *(short8*)(Wp + (long)chunk * 8) = v;
}

// ---------------------------------------------------------------------------
// K1: QKV projection via MFMA. M=8192 tokens, K=256, N=128 (x3 outputs).
// 128 blocks x 256 threads (4 waves); wave w owns tokens i0+w*16..+15.
// A-frags built in-register from coalesced fp32 loads (query for Q, context
// for K and V — context frag shared). B-frags are prepacked contiguous 16B.
// Q,K stored [bh][n][32]; V transposed to [bh][32][n] via padded LDS tile.
// ---------------------------------------------------------------------------
__global__ __launch_bounds__(256) void qkv_kernel(
    const float* __restrict__ query, const float* __restrict__ context,
    const unsigned short* __restrict__ Wp,
    unsigned short* __restrict__ Qb, unsigned short* __restrict__ Kb,
    unsigned short* __restrict__ Vb)
{
    __shared__ __align__(16) unsigned short V_lds[128 * 72];  // [col][token] 18KB

    const int tid = threadIdx.x;
    const int w = tid >> 6, lane = tid & 63;
    const int quad = lane >> 4, l15 = lane & 15;
    const long i0 = (long)blockIdx.x * 64;
    const long row = i0 + w * 16 + l15;

    const unsigned short* Wqp = Wp;
    const unsigned short* Wkp = Wp + 32768;
    const unsigned short* Wvp = Wp + 65536;

    floatx4 aQ[8] = {}, aK[8] = {}, aV[8] = {};

    for (int s = 0; s < 8; s++) {
        const float* qp = query + row * C_DIM + s * 32 + quad * 8;
        const float* cp = context + row * C_DIM + s * 32 + quad * 8;
        floatx4 q0 = *(const floatx4*)qp, q1 = *(const floatx4*)(qp + 4);
        floatx4 c0 = *(const floatx4*)cp, c1 = *(const floatx4*)(cp + 4);
        short8 aq, ac;
        #pragma unroll
        for (int j = 0; j < 4; j++) {
            aq[j] = (short)f2bf(q0[j]); aq[4 + j] = (short)f2bf(q1[j]);
            ac[j] = (short)f2bf(c0[j]); ac[4 + j] = (short)f2bf(c1[j]);
        }
        #pragma unroll
        for (int t = 0; t < 8; t++) {
            const long fo = ((long)(s * 8 + t) * 64 + lane) * 8;
            short8 bq = *(const short8*)(Wqp + fo);
            short8 bk = *(const short8*)(Wkp + fo);
            short8 bv = *(const short8*)(Wvp + fo);
            aQ[t] = __builtin_amdgcn_mfma_f32_16x16x32_bf16(aq, bq, aQ[t], 0, 0, 0);
            aK[t] = __builtin_amdgcn_mfma_f32_16x16x32_bf16(ac, bk, aK[t], 0, 0, 0);
            aV[t] = __builtin_amdgcn_mfma_f32_16x16x32_bf16(ac, bv, aV[t], 0, 0, 0);
        }
    }

    // epilogue: Q,K direct scalar bf16 stores; V into LDS for transpose
    const long b = i0 >> 12;
    const long n0 = i0 & (N_TOK - 1);          // token base within batch
    const long nbase = n0 + w * 16 + quad * 4;
    #pragma unroll
    for (int t = 0; t < 8; t++) {
        const int col = t * 16 + l15;
        const int h = col >> 5, d = col & 31;
        unsigned short* qdst = Qb + ((b * HEADS + h) * N_TOK + nbase) * HD + d;
        unsigned short* kdst = Kb + ((b * HEADS + h) * N_TOK + nbase) * HD + d;
        #pragma unroll
        for (int r = 0; r < 4; r++) {
            qdst[r * HD] = f2bf(aQ[t][r]);
            kdst[r * HD] = f2bf(aK[t][r]);
        }
        short4_t pv;
        #pragma unroll
        for (int r = 0; r < 4; r++) pv[r] = (short)f2bf(aV[t][r]);
        *(short4_t*)&V_lds[col * 72 + w * 16 + quad * 4] = pv;
    }
    __syncthreads();

    // cooperative V^T write-out: 128 rows x 64 tokens, contiguous 16B chunks
    {
        const int rr = tid >> 1;                 // 0..127 (head-major col)
        const int h = rr >> 5, d = rr & 31;
        // BUGFIX (round 3): token index must be n0 (= i0 mod N_TOK), not i0 —
        // batch-1 blocks wrote one d-row too high, garbling V for b=1.
        unsigned short* dst = Vb + ((b * HEADS + h) * HD + d) * N_TOK + n0 + (tid & 1) * 32;
        const unsigned short* srcp = &V_lds[rr * 72 + (tid & 1) * 32];
        #pragma unroll
        for (int cc = 0; cc < 4; cc++)
            *(short8*)(dst + cc * 8) = *(const short8*)(srcp + cc * 8);
    }
}

// ---------------------------------------------------------------------------
// K2: flash attention, no-max softmax, split-K=2 (unchanged from round 2).
// ---------------------------------------------------------------------------
__global__ __launch_bounds__(256, 2) void attn_kernel(
    const unsigned short* __restrict__ Qb, const unsigned short* __restrict__ Kb,
    const unsigned short* __restrict__ Vb,
    unsigned short* __restrict__ AO, float* __restrict__ Lbuf)
{
    __shared__ __align__(16) unsigned short K_lds[64 * KS];
    __shared__ __align__(16) unsigned short V_lds[HD * VS];
    __shared__ __align__(16) unsigned short P_lds[4][2 * 16 * PS];

    const int tid  = threadIdx.x;
    const int w    = tid >> 6;
    const int lane = tid & 63;
    const int quad = lane >> 4;
    const int l15  = lane & 15;
    const int bh   = blockIdx.y;
    const int z    = blockIdx.z;
    const int i0   = blockIdx.x * 128 + w * 32;

    const unsigned short* Qh = Qb + (long)bh * N_TOK * HD;
    const unsigned short* Kh = Kb + (long)bh * N_TOK * HD;
    const unsigned short* Vh = Vb + (long)bh * HD * N_TOK;

    const short8 qfA = *(const short8*)(Qh + (long)(i0 + l15) * HD + quad * 8);
    const short8 qfB = *(const short8*)(Qh + (long)(i0 + 16 + l15) * HD + quad * 8);

    floatx4 accA0 = {0.f,0.f,0.f,0.f}, accA1 = {0.f,0.f,0.f,0.f};
    floatx4 accB0 = {0.f,0.f,0.f,0.f}, accB1 = {0.f,0.f,0.f,0.f};
    floatx4 lA = {0.f,0.f,0.f,0.f}, lB = {0.f,0.f,0.f,0.f};

    const int  kst = (tid >> 2) * KS + (tid & 3) * 8;
    const int  vst = (tid >> 3) * VS + (tid & 7) * 8;
    const long vgl = (long)(tid >> 3) * N_TOK + (tid & 7) * 8;
    unsigned short* Pw  = P_lds[w];
    unsigned short* PwB = P_lds[w] + 16 * PS;

    const int j_lo = z * KEYS_PER_SPLIT, j_hi = j_lo + KEYS_PER_SPLIT;
    for (int j0 = j_lo; j0 < j_hi; j0 += 64) {
        __syncthreads();
        *(short8*)&K_lds[kst] = *(const short8*)(Kh + (long)j0 * HD + tid * 8);
        *(short8*)&V_lds[vst] = *(const short8*)(Vh + vgl + j0);
        __syncthreads();

        #pragma unroll
        for (int sub = 0; sub < 2; sub++) {
            const int jb = sub * 32;
            short8 kf0 = *(short8*)&K_lds[(jb + l15) * KS + quad * 8];
            short8 kf1 = *(short8*)&K_lds[(jb + 16 + l15) * KS + quad * 8];
            const floatx4 zf = {0.f,0.f,0.f,0.f};
            floatx4 sA0 = __builtin_amdgcn_mfma_f32_16x16x32_bf16(qfA, kf0, zf, 0, 0, 0);
            floatx4 sA1 = __builtin_amdgcn_mfma_f32_16x16x32_bf16(qfA, kf1, zf, 0, 0, 0);
            floatx4 sB0 = __builtin_amdgcn_mfma_f32_16x16x32_bf16(qfB, kf0, zf, 0, 0, 0);
            floatx4 sB1 = __builtin_amdgcn_mfma_f32_16x16x32_bf16(qfB, kf1, zf, 0, 0, 0);

            floatx4 pA0, pA1, pB0, pB1;
            #pragma unroll
            for (int r = 0; r < 4; r++) {
                pA0[r] = __builtin_amdgcn_exp2f(sA0[r]);
                pA1[r] = __builtin_amdgcn_exp2f(sA1[r]);
                pB0[r] = __builtin_amdgcn_exp2f(sB0[r]);
                pB1[r] = __builtin_amdgcn_exp2f(sB1[r]);
                lA[r] += pA0[r] + pA1[r];
                lB[r] += pB0[r] + pB1[r];
            }

            #pragma unroll
            for (int r = 0; r < 4; r++) {
                const int rw = (quad * 4 + r) * PS;
                Pw[rw + l15]       = f2bf(pA0[r]);
                Pw[rw + 16 + l15]  = f2bf(pA1[r]);
                PwB[rw + l15]      = f2bf(pB0[r]);
                PwB[rw + 16 + l15] = f2bf(pB1[r]);
            }
            short8 pfA = *(short8*)&Pw[l15 * PS + quad * 8];
            short8 pfB = *(short8*)&PwB[l15 * PS + quad * 8];

            short8 vf0 = *(short8*)&V_lds[l15 * VS + jb + quad * 8];
            short8 vf1 = *(short8*)&V_lds[(16 + l15) * VS + jb + quad * 8];
            accA0 = __builtin_amdgcn_mfma_f32_16x16x32_bf16(pfA, vf0, accA0, 0, 0, 0);
            accA1 = __builtin_amdgcn_mfma_f32_16x16x32_bf16(pfA, vf1, accA1, 0, 0, 0);
            accB0 = __builtin_amdgcn_mfma_f32_16x16x32_bf16(pfB, vf0, accB0, 0, 0, 0);
            accB1 = __builtin_amdgcn_mfma_f32_16x16x32_bf16(pfB, vf1, accB1, 0, 0, 0);
        }
    }

    #pragma unroll
    for (int off = 1; off < 16; off <<= 1) {
        #pragma unroll
        for (int r = 0; r < 4; r++) {
            lA[r] += __shfl_xor(lA[r], off);
            lB[r] += __shfl_xor(lB[r], off);
        }
    }

    const int b = bh >> 2, h = bh & 3;
    unsigned short* AOz = AO + (long)z * (NBAT * N_TOK * A_DIM);
    float* Lz = Lbuf + (long)z * (BH * N_TOK);
    #pragma unroll
    for (int r = 0; r < 4; r++) {
        const float invA = 1.0f / lA[r];
        const float invB = 1.0f / lB[r];
        const long rowA = (long)b * N_TOK + i0 + quad * 4 + r;
        const long rowB = rowA + 16;
        AOz[rowA * A_DIM + h * HD + l15]      = f2bf(accA0[r] * invA);
        AOz[rowA * A_DIM + h * HD + 16 + l15] = f2bf(accA1[r] * invA);
        AOz[rowB * A_DIM + h * HD + l15]      = f2bf(accB0[r] * invB);
        AOz[rowB * A_DIM + h * HD + 16 + l15] = f2bf(accB1[r] * invB);
        if (l15 == 0) {
            Lz[(long)bh * N_TOK + i0 + quad * 4 + r]      = lA[r];
            Lz[(long)bh * N_TOK + i0 + 16 + quad * 4 + r] = lB[r];
        }
    }
}

// ---------------------------------------------------------------------------
// K3: split-K combine + out-projection via MFMA. M=8192, K=128, N=256.
// 128 blocks x 4 waves; wave owns 16 rows. A-frags combined from the two
// split partials (l-weighted) in fp32, rounded to bf16.
// ---------------------------------------------------------------------------
__global__ __launch_bounds__(256) void outproj_kernel(
    const unsigned short* __restrict__ AO, const float* __restrict__ Lbuf,
    const unsigned short* __restrict__ Wp, float* __restrict__ out)
{
    const int tid = threadIdx.x;
    const int w = tid >> 6, lane = tid & 63;
    const int quad = lane >> 4, l15 = lane & 15;
    const long i0 = (long)blockIdx.x * 64;
    const long row = i0 + w * 16 + l15;
    const int b = (int)(row >> 12);
    const int n = (int)(row & (N_TOK - 1));
    const unsigned short* Wop = Wp + 98304;

    floatx4 acc[16] = {};

    #pragma unroll
    for (int s = 0; s < 4; s++) {   // k-step == head s (32-aligned)
        const float l0 = Lbuf[(long)(b * HEADS + s) * N_TOK + n];
        const float l1 = Lbuf[(long)BH * N_TOK + (long)(b * HEADS + s) * N_TOK + n];
        const float inv = 1.0f / (l0 + l1);
        const float w0 = l0 * inv, w1 = l1 * inv;
        short8 a0 = *(const short8*)(AO + row * A_DIM + s * 32 + quad * 8);
        short8 a1 = *(const short8*)(AO + (long)NBAT * N_TOK * A_DIM + row * A_DIM + s * 32 + quad * 8);
        short8 af;
        #pragma unroll
        for (int j = 0; j < 8; j++)
            af[j] = (short)f2bf(w0 * bf2f((unsigned short)a0[j]) +
                                w1 * bf2f((unsigned short)a1[j]));
        #pragma unroll
        for (int t = 0; t < 16; t++) {
            short8 bo = *(const short8*)(Wop + ((long)(s * 16 + t) * 64 + lane) * 8);
            acc[t] = __builtin_amdgcn_mfma_f32_16x16x32_bf16(af, bo, acc[t], 0, 0, 0);
        }
    }

    #pragma unroll
    for (int t = 0; t < 16; t++) {
        #pragma unroll
        for (int r = 0; r < 4; r++)
            out[(i0 + w * 16 + quad * 4 + r) * C_DIM + t * 16 + l15] = acc[t][r];
    }
}

// ---------------------------------------------------------------------------
extern "C" void kernel_launch(void* const* d_in, const int* in_sizes, int n_in,
                              void* d_out, int out_size, void* d_ws, size_t ws_size,
                              hipStream_t stream)
{
    const float* query   = (const float*)d_in[0];
    const float* context = (const float*)d_in[1];
    const float* Wq      = (const float*)d_in[2];
    const float* Wk      = (const float*)d_in[3];
    const float* Wv      = (const float*)d_in[4];
    const float* Wo      = (const float*)d_in[5];
    float* out = (float*)d_out;

    char* ws = (char*)d_ws;
    unsigned short* Qb = (unsigned short*)(ws);                    // 2 MB [bh][n][32]
    unsigned short* Kb = (unsigned short*)(ws + (2 << 20));        // 2 MB [bh][n][32]
    unsigned short* Vb = (unsigned short*)(ws + (4 << 20));        // 2 MB [bh][32][n]
    unsigned short* AO = (unsigned short*)(ws + (6 << 20));        // 4 MB [2][b*n][128] bf16
    float*          Lb = (float*)(ws + (10 << 20));                // 256 KB [2][bh][n]
    unsigned short* Wp = (unsigned short*)(ws + (10 << 20) + (256 << 10)); // 256 KB packed

    wpack_kernel<<<dim3(64), dim3(256), 0, stream>>>(Wq, Wk, Wv, Wo, Wp);
    qkv_kernel<<<dim3(128), dim3(256), 0, stream>>>(query, context, Wp, Qb, Kb, Vb);
    attn_kernel<<<dim3(N_TOK / 128, BH, SPLITS), dim3(256), 0, stream>>>(
        Qb, Kb, Vb, AO, Lb);
    outproj_kernel<<<dim3(128), dim3(256), 0, stream>>>(AO, Lb, Wp, out);
}

// Round 5
// 162.231 us; speedup vs baseline: 1.3879x; 1.0527x over previous
//
#include <hip/hip_runtime.h>
#include <hip/hip_bf16.h>
#include <math.h>

// Problem constants (fixed by reference: b=2, h=w=64, dim=256, attn_dim=128, HEAD=4)
#define N_TOK 4096
#define C_DIM 256
#define A_DIM 128
#define HEADS 4
#define HD    32
#define NBAT  2
#define BH    (NBAT * HEADS)

// (1/sqrt(32)) * log2(e) — folded into Wq at pack time
#define SCALE_LOG2E 0.25503521f

#define SPLITS 4
#define KEYS_PER_SPLIT (N_TOK / SPLITS)

// padded LDS strides for attention (shorts)
#define KS 36
#define VS 72
#define PS 36

typedef __attribute__((ext_vector_type(8))) short short8;   // 8 bf16 frag
typedef __attribute__((ext_vector_type(4))) short short4_t; // 4 bf16
typedef __attribute__((ext_vector_type(4))) float floatx4;  // MFMA C/D frag

__device__ __forceinline__ unsigned short f2bf(float f) {   // RNE
    unsigned int u = __float_as_uint(f);
    u = (u + 0x7fffu + ((u >> 16) & 1u)) >> 16;
    return (unsigned short)u;
}
__device__ __forceinline__ unsigned short f2bf_pos(float f) { // cheap RN (positive vals)
    return (unsigned short)((__float_as_uint(f) + 0x8000u) >> 16);
}
__device__ __forceinline__ float bf2f(unsigned short u) {
    return __uint_as_float((unsigned int)u << 16);
}

// ---------------------------------------------------------------------------
// K0: pack weights fp32 -> bf16 in B-fragment order.
// Layout: Wp[wid][step s][tile t][lane][j]  (wid: 0=Wq(scaled) 1=Wk 2=Wv 3=Wo)
// B-frag semantics: lane=(quad,l15) holds B[k = quad*8+j][n = t*16+l15].
// ---------------------------------------------------------------------------
__global__ __launch_bounds__(256) void wpack_kernel(
    const float* __restrict__ Wq, const float* __restrict__ Wk,
    const float* __restrict__ Wv, const float* __restrict__ Wo,
    unsigned short* __restrict__ Wp)
{
    const int chunk = blockIdx.x * 256 + threadIdx.x;  // [0, 16384): 8 shorts each
    const int wid = chunk >> 12;
    const int c = chunk & 4095;
    const int lane = c & 63, quad = lane >> 4, l15 = lane & 15;
    short8 v;
    if (wid < 3) {
        const int s = c >> 9, t = (c >> 6) & 7;
        const float* W = (wid == 0) ? Wq : ((wid == 1) ? Wk : Wv);
        const float scale = (wid == 0) ? SCALE_LOG2E : 1.0f;
        const int src = (s * 32 + quad * 8) * A_DIM + t * 16 + l15;
        #pragma unroll
        for (int j = 0; j < 8; j++) v[j] = (short)f2bf(W[src + j * A_DIM] * scale);
    } else {
        const int s = c >> 10, t = (c >> 6) & 15;
        const int src = (s * 32 + quad * 8) * C_DIM + t * 16 + l15;
        #pragma unroll
        for (int j = 0; j < 8; j++) v[j] = (short)f2bf(Wo[src + j * C_DIM]);
    }
    *(short8*)(Wp + (long)chunk * 8) = v;
}

// ---------------------------------------------------------------------------
// K1: QKV projection via MFMA. 256 blocks x 4 waves.
// Block covers 32 rows x 128 cols; wave (rt = w>>1, ch = w&1) owns 16 rows x
// 64 cols x {Q,K,V} (12 accumulators). A-frags built in-register from fp32;
// B-frags prepacked. Q,K stored [bh][n][32]; V transposed via LDS.
// ---------------------------------------------------------------------------
__global__ __launch_bounds__(256) void qkv_kernel(
    const float* __restrict__ query, const float* __restrict__ context,
    const unsigned short* __restrict__ Wp,
    unsigned short* __restrict__ Qb, unsigned short* __restrict__ Kb,
    unsigned short* __restrict__ Vb)
{
    __shared__ __align__(16) unsigned short V_lds[128 * 36];  // [col][tok32+pad] 9KB

    const int tid = threadIdx.x;
    const int w = tid >> 6, lane = tid & 63;
    const int quad = lane >> 4, l15 = lane & 15;
    const int rt = w >> 1, ch = w & 1;
    const long i0 = (long)blockIdx.x * 32;
    const long row = i0 + rt * 16 + l15;

    const unsigned short* Wqp = Wp;
    const unsigned short* Wkp = Wp + 32768;
    const unsigned short* Wvp = Wp + 65536;

    floatx4 aQ[4] = {}, aK[4] = {}, aV[4] = {};

    for (int s = 0; s < 8; s++) {
        const float* qp = query + row * C_DIM + s * 32 + quad * 8;
        const float* cp = context + row * C_DIM + s * 32 + quad * 8;
        floatx4 q0 = *(const floatx4*)qp, q1 = *(const floatx4*)(qp + 4);
        floatx4 c0 = *(const floatx4*)cp, c1 = *(const floatx4*)(cp + 4);
        short8 aq, ac;
        #pragma unroll
        for (int j = 0; j < 4; j++) {
            aq[j] = (short)f2bf(q0[j]); aq[4 + j] = (short)f2bf(q1[j]);
            ac[j] = (short)f2bf(c0[j]); ac[4 + j] = (short)f2bf(c1[j]);
        }
        #pragma unroll
        for (int tp = 0; tp < 4; tp++) {
            const long fo = ((long)(s * 8 + ch * 4 + tp) * 64 + lane) * 8;
            short8 bq = *(const short8*)(Wqp + fo);
            short8 bk = *(const short8*)(Wkp + fo);
            short8 bv = *(const short8*)(Wvp + fo);
            aQ[tp] = __builtin_amdgcn_mfma_f32_16x16x32_bf16(aq, bq, aQ[tp], 0, 0, 0);
            aK[tp] = __builtin_amdgcn_mfma_f32_16x16x32_bf16(ac, bk, aK[tp], 0, 0, 0);
            aV[tp] = __builtin_amdgcn_mfma_f32_16x16x32_bf16(ac, bv, aV[tp], 0, 0, 0);
        }
    }

    const long b = i0 >> 12;
    const long n0 = i0 & (N_TOK - 1);
    const long nbase = n0 + rt * 16 + quad * 4;
    #pragma unroll
    for (int tp = 0; tp < 4; tp++) {
        const int col = ch * 64 + tp * 16 + l15;
        const int h = col >> 5, d = col & 31;
        unsigned short* qdst = Qb + ((b * HEADS + h) * N_TOK + nbase) * HD + d;
        unsigned short* kdst = Kb + ((b * HEADS + h) * N_TOK + nbase) * HD + d;
        #pragma unroll
        for (int r = 0; r < 4; r++) {
            qdst[r * HD] = f2bf(aQ[tp][r]);
            kdst[r * HD] = f2bf(aK[tp][r]);
        }
        short4_t pv;
        #pragma unroll
        for (int r = 0; r < 4; r++) pv[r] = (short)f2bf(aV[tp][r]);
        *(short4_t*)&V_lds[col * 36 + rt * 16 + quad * 4] = pv;
    }
    __syncthreads();

    {   // cooperative V^T write-out: 128 cols x 32 tokens; 32B chunks
        const int col = tid >> 1, seg = tid & 1;
        const int h = col >> 5, d = col & 31;
        unsigned short* dst = Vb + ((b * HEADS + h) * HD + d) * N_TOK + n0 + seg * 16;
        const unsigned short* srcp = &V_lds[col * 36 + seg * 16];
        *(short8*)dst = *(const short8*)srcp;
        *(short8*)(dst + 8) = *(const short8*)(srcp + 8);
    }
}

// ---------------------------------------------------------------------------
// K2: flash attention, no-max softmax, split-K=4.
// Grid (32 qblocks, 8 bh, 4 splits) = 1024 blocks, 4 blocks/CU (16 waves/CU).
// Register prefetch of next K/V tile overlaps global latency with compute.
// ---------------------------------------------------------------------------
__global__ __launch_bounds__(256, 4) void attn_kernel(
    const unsigned short* __restrict__ Qb, const unsigned short* __restrict__ Kb,
    const unsigned short* __restrict__ Vb,
    unsigned short* __restrict__ AO, float* __restrict__ Lbuf)
{
    __shared__ __align__(16) unsigned short K_lds[64 * KS];        // 4.5 KB
    __shared__ __align__(16) unsigned short V_lds[HD * VS];        // 4.5 KB
    __shared__ __align__(16) unsigned short P_lds[4][2 * 16 * PS]; // 9 KB

    const int tid  = threadIdx.x;
    const int w    = tid >> 6;
    const int lane = tid & 63;
    const int quad = lane >> 4;
    const int l15  = lane & 15;
    const int bh   = blockIdx.y;
    const int z    = blockIdx.z;
    const int i0   = blockIdx.x * 128 + w * 32;

    const unsigned short* Qh = Qb + (long)bh * N_TOK * HD;
    const unsigned short* Kh = Kb + (long)bh * N_TOK * HD;
    const unsigned short* Vh = Vb + (long)bh * HD * N_TOK;

    const short8 qfA = *(const short8*)(Qh + (long)(i0 + l15) * HD + quad * 8);
    const short8 qfB = *(const short8*)(Qh + (long)(i0 + 16 + l15) * HD + quad * 8);

    floatx4 accA0 = {0.f,0.f,0.f,0.f}, accA1 = {0.f,0.f,0.f,0.f};
    floatx4 accB0 = {0.f,0.f,0.f,0.f}, accB1 = {0.f,0.f,0.f,0.f};
    floatx4 lA = {0.f,0.f,0.f,0.f}, lB = {0.f,0.f,0.f,0.f};

    const int  kst = (tid >> 2) * KS + (tid & 3) * 8;
    const int  vst = (tid >> 3) * VS + (tid & 7) * 8;
    const long vgl = (long)(tid >> 3) * N_TOK + (tid & 7) * 8;
    unsigned short* Pw  = P_lds[w];
    unsigned short* PwB = P_lds[w] + 16 * PS;

    const int j_lo = z * KEYS_PER_SPLIT, j_hi = j_lo + KEYS_PER_SPLIT;

    // prefetch tile 0 into registers
    short8 kreg = *(const short8*)(Kh + (long)j_lo * HD + tid * 8);
    short8 vreg = *(const short8*)(Vh + vgl + j_lo);

    for (int j0 = j_lo; j0 < j_hi; j0 += 64) {
        __syncthreads();
        *(short8*)&K_lds[kst] = kreg;
        *(short8*)&V_lds[vst] = vreg;
        if (j0 + 64 < j_hi) {   // prefetch next tile (overlaps with compute)
            kreg = *(const short8*)(Kh + (long)(j0 + 64) * HD + tid * 8);
            vreg = *(const short8*)(Vh + vgl + j0 + 64);
        }
        __syncthreads();

        #pragma unroll
        for (int sub = 0; sub < 2; sub++) {
            const int jb = sub * 32;
            short8 kf0 = *(short8*)&K_lds[(jb + l15) * KS + quad * 8];
            short8 kf1 = *(short8*)&K_lds[(jb + 16 + l15) * KS + quad * 8];
            const floatx4 zf = {0.f,0.f,0.f,0.f};
            floatx4 sA0 = __builtin_amdgcn_mfma_f32_16x16x32_bf16(qfA, kf0, zf, 0, 0, 0);
            floatx4 sA1 = __builtin_amdgcn_mfma_f32_16x16x32_bf16(qfA, kf1, zf, 0, 0, 0);
            floatx4 sB0 = __builtin_amdgcn_mfma_f32_16x16x32_bf16(qfB, kf0, zf, 0, 0, 0);
            floatx4 sB1 = __builtin_amdgcn_mfma_f32_16x16x32_bf16(qfB, kf1, zf, 0, 0, 0);

            floatx4 pA0, pA1, pB0, pB1;
            #pragma unroll
            for (int r = 0; r < 4; r++) {
                pA0[r] = __builtin_amdgcn_exp2f(sA0[r]);
                pA1[r] = __builtin_amdgcn_exp2f(sA1[r]);
                pB0[r] = __builtin_amdgcn_exp2f(sB0[r]);
                pB1[r] = __builtin_amdgcn_exp2f(sB1[r]);
                lA[r] += pA0[r] + pA1[r];
                lB[r] += pB0[r] + pB1[r];
            }

            #pragma unroll
            for (int r = 0; r < 4; r++) {
                const int rw = (quad * 4 + r) * PS;
                Pw[rw + l15]       = f2bf_pos(pA0[r]);
                Pw[rw + 16 + l15]  = f2bf_pos(pA1[r]);
                PwB[rw + l15]      = f2bf_pos(pB0[r]);
                PwB[rw + 16 + l15] = f2bf_pos(pB1[r]);
            }
            short8 pfA = *(short8*)&Pw[l15 * PS + quad * 8];
            short8 pfB = *(short8*)&PwB[l15 * PS + quad * 8];

            short8 vf0 = *(short8*)&V_lds[l15 * VS + jb + quad * 8];
            short8 vf1 = *(short8*)&V_lds[(16 + l15) * VS + jb + quad * 8];
            accA0 = __builtin_amdgcn_mfma_f32_16x16x32_bf16(pfA, vf0, accA0, 0, 0, 0);
            accA1 = __builtin_amdgcn_mfma_f32_16x16x32_bf16(pfA, vf1, accA1, 0, 0, 0);
            accB0 = __builtin_amdgcn_mfma_f32_16x16x32_bf16(pfB, vf0, accB0, 0, 0, 0);
            accB1 = __builtin_amdgcn_mfma_f32_16x16x32_bf16(pfB, vf1, accB1, 0, 0, 0);
        }
    }

    #pragma unroll
    for (int off = 1; off < 16; off <<= 1) {
        #pragma unroll
        for (int r = 0; r < 4; r++) {
            lA[r] += __shfl_xor(lA[r], off);
            lB[r] += __shfl_xor(lB[r], off);
        }
    }

    const int b = bh >> 2, h = bh & 3;
    unsigned short* AOz = AO + (long)z * (NBAT * N_TOK * A_DIM);
    float* Lz = Lbuf + (long)z * (BH * N_TOK);
    #pragma unroll
    for (int r = 0; r < 4; r++) {
        const float invA = 1.0f / lA[r];
        const float invB = 1.0f / lB[r];
        const long rowA = (long)b * N_TOK + i0 + quad * 4 + r;
        const long rowB = rowA + 16;
        AOz[rowA * A_DIM + h * HD + l15]      = f2bf(accA0[r] * invA);
        AOz[rowA * A_DIM + h * HD + 16 + l15] = f2bf(accA1[r] * invA);
        AOz[rowB * A_DIM + h * HD + l15]      = f2bf(accB0[r] * invB);
        AOz[rowB * A_DIM + h * HD + 16 + l15] = f2bf(accB1[r] * invB);
        if (l15 == 0) {
            Lz[(long)bh * N_TOK + i0 + quad * 4 + r]      = lA[r];
            Lz[(long)bh * N_TOK + i0 + 16 + quad * 4 + r] = lB[r];
        }
    }
}

// ---------------------------------------------------------------------------
// K3: split-K combine + out-projection via MFMA. 256 blocks x 4 waves.
// Block covers 32 rows x 256 cols; wave (rt, ch) owns 16 rows x 128 cols.
// ---------------------------------------------------------------------------
__global__ __launch_bounds__(256) void outproj_kernel(
    const unsigned short* __restrict__ AO, const float* __restrict__ Lbuf,
    const unsigned short* __restrict__ Wp, float* __restrict__ out)
{
    const int tid = threadIdx.x;
    const int w = tid >> 6, lane = tid & 63;
    const int quad = lane >> 4, l15 = lane & 15;
    const int rt = w >> 1, ch = w & 1;
    const long i0 = (long)blockIdx.x * 32;
    const long row = i0 + rt * 16 + l15;
    const int b = (int)(row >> 12);
    const int n = (int)(row & (N_TOK - 1));
    const unsigned short* Wop = Wp + 98304;

    floatx4 acc[8] = {};

    #pragma unroll
    for (int s = 0; s < 4; s++) {   // k-step == head s (32-aligned)
        float lz[SPLITS], lsum = 0.f;
        #pragma unroll
        for (int z = 0; z < SPLITS; z++) {
            lz[z] = Lbuf[(long)z * (BH * N_TOK) + (long)(b * HEADS + s) * N_TOK + n];
            lsum += lz[z];
        }
        const float inv = 1.0f / lsum;
        float vals[8] = {};
        #pragma unroll
        for (int z = 0; z < SPLITS; z++) {
            short8 az = *(const short8*)(AO + (long)z * (NBAT * N_TOK * A_DIM) +
                                         row * A_DIM + s * 32 + quad * 8);
            const float wz = lz[z] * inv;
            #pragma unroll
            for (int j = 0; j < 8; j++) vals[j] += wz * bf2f((unsigned short)az[j]);
        }
        short8 af;
        #pragma unroll
        for (int j = 0; j < 8; j++) af[j] = (short)f2bf(vals[j]);
        #pragma unroll
        for (int tp = 0; tp < 8; tp++) {
            const int t = ch * 8 + tp;
            short8 bo = *(const short8*)(Wop + ((long)(s * 16 + t) * 64 + lane) * 8);
            acc[tp] = __builtin_amdgcn_mfma_f32_16x16x32_bf16(af, bo, acc[tp], 0, 0, 0);
        }
    }

    #pragma unroll
    for (int tp = 0; tp < 8; tp++) {
        #pragma unroll
        for (int r = 0; r < 4; r++)
            out[(i0 + rt * 16 + quad * 4 + r) * C_DIM + (ch * 8 + tp) * 16 + l15] = acc[tp][r];
    }
}

// ---------------------------------------------------------------------------
extern "C" void kernel_launch(void* const* d_in, const int* in_sizes, int n_in,
                              void* d_out, int out_size, void* d_ws, size_t ws_size,
                              hipStream_t stream)
{
    const float* query   = (const float*)d_in[0];
    const float* context = (const float*)d_in[1];
    const float* Wq      = (const float*)d_in[2];
    const float* Wk      = (const float*)d_in[3];
    const float* Wv      = (const float*)d_in[4];
    const float* Wo      = (const float*)d_in[5];
    float* out = (float*)d_out;

    char* ws = (char*)d_ws;
    unsigned short* Qb = (unsigned short*)(ws);                    // 2 MB [bh][n][32]
    unsigned short* Kb = (unsigned short*)(ws + (2 << 20));        // 2 MB [bh][n][32]
    unsigned short* Vb = (unsigned short*)(ws + (4 << 20));        // 2 MB [bh][32][n]
    unsigned short* AO = (unsigned short*)(ws + (6 << 20));        // 8 MB [4][b*n][128] bf16
    float*          Lb = (float*)(ws + (14 << 20));                // 512 KB [4][bh][n]
    unsigned short* Wp = (unsigned short*)(ws + (14 << 20) + (512 << 10)); // 256 KB packed

    wpack_kernel<<<dim3(64), dim3(256), 0, stream>>>(Wq, Wk, Wv, Wo, Wp);
    qkv_kernel<<<dim3(256), dim3(256), 0, stream>>>(query, context, Wp, Qb, Kb, Vb);
    attn_kernel<<<dim3(N_TOK / 128, BH, SPLITS), dim3(256), 0, stream>>>(
        Qb, Kb, Vb, AO, Lb);
    outproj_kernel<<<dim3(256), dim3(256), 0, stream>>>(AO, Lb, Wp, out);
}